// Round 3
// baseline (2803.359 us; speedup 1.0000x reference)
//
#include <hip/hip_runtime.h>
#include <math.h>

#define HO 15
#define LBL 21
#define MIX 5
#define LM 105   // LBL*MIX
#define NB 256   // grid blocks == CU count -> co-residency guaranteed
#define NT 256   // threads per block
#define GSZ (NB * NT)
#define NWV (GSZ / 64)

struct Params {
    const float* x;
    const float* w[14]; const float* b[14];   // 1..13 used
    const float *wf1, *bf1, *wf2, *bf2, *wf3, *bf3;
    const float *wl, *bl, *wa, *ba, *wm, *bm, *wb, *bb;
    float *A, *B, *v, *h1, *h3, *out;
    int* bar;
};

__device__ __forceinline__ float max4(float a, float b, float c, float d) {
    return fmaxf(fmaxf(a, b), fmaxf(c, d));
}

// ---- software grid barrier (one counter per sync point, zeroed pre-launch) ----
__device__ __forceinline__ void gbar(int* bar, int id) {
    __syncthreads();
    if (threadIdx.x == 0) {
        __threadfence();  // agent-scope release of this block's global writes
        int* c = bar + id;
        int prev = __hip_atomic_fetch_add(c, 1, __ATOMIC_ACQ_REL, __HIP_MEMORY_SCOPE_AGENT);
        if (prev + 1 < NB) {
            while (__hip_atomic_load(c, __ATOMIC_ACQUIRE, __HIP_MEMORY_SCOPE_AGENT) < NB)
                __builtin_amdgcn_s_sleep(4);
        }
        __threadfence();  // agent-scope acquire for subsequent reads
    }
    __syncthreads();
}

// ---- 3x3 conv (pad 1) + relu; POOL=2 reads a 2x2-maxpooled view of input ----
template <int POOL>
__device__ void convstage(const float* __restrict__ in, const float* __restrict__ w,
                          const float* __restrict__ bias, float* __restrict__ out,
                          int Cin, int Cout, int Hi, int H, int gtid) {
    int total = 2 * Cout * H * H;
    for (int idx = gtid; idx < total; idx += GSZ) {
        int x = idx % H; int t = idx / H;
        int y = t % H; t /= H;
        int o = t % Cout; int b = t / Cout;
        const float* ip = in + (size_t)b * Cin * Hi * Hi;
        const float* wp = w + (size_t)o * Cin * 9;
        float acc = bias[o];
        for (int c = 0; c < Cin; ++c) {
            const float* ic = ip + (size_t)c * Hi * Hi;
            const float* wc = wp + c * 9;
#pragma unroll
            for (int ky = 0; ky < 3; ++ky) {
                int yy = y + ky - 1;
                if (yy < 0 || yy >= H) continue;
#pragma unroll
                for (int kx = 0; kx < 3; ++kx) {
                    int xx = x + kx - 1;
                    if (xx < 0 || xx >= H) continue;
                    float val;
                    if (POOL == 1) {
                        val = ic[yy * Hi + xx];
                    } else {
                        const float* q = ic + (2 * yy) * Hi + 2 * xx;
                        val = max4(q[0], q[1], q[Hi], q[Hi + 1]);
                    }
                    acc += val * wc[ky * 3 + kx];
                }
            }
        }
        out[idx] = fmaxf(acc, 0.f);
    }
}

// ---- strided-tap matvec; POOL=2 maxpools a [3][3] per-channel input ----
template <int ACT, int POOL>
__device__ void mvstage(const float* __restrict__ in, const float* __restrict__ w,
                        const float* __restrict__ bias, float* __restrict__ out,
                        int Cin, int Cout, int S, int F, int wv, int lane) {
    for (int t = wv; t < 2 * Cout; t += NWV) {
        int b = t / Cout, o = t % Cout;
        float acc = 0.f;
        for (int c = lane; c < Cin; c += 64) {
            float iv;
            if (POOL == 2) {
                const float* q = in + ((size_t)b * Cin + c) * 9;
                iv = max4(q[0], q[1], q[3], q[4]);
            } else {
                iv = in[(size_t)b * Cin + c];
            }
            acc += w[((size_t)o * Cin + c) * S + F] * iv;
        }
#pragma unroll
        for (int off = 32; off; off >>= 1) acc += __shfl_xor(acc, off);
        if (lane == 0) {
            acc += bias[o];
            if (ACT == 1) acc = fmaxf(acc, 0.f);
            if (ACT == 2) acc = 1.f / (1.f + expf(-acc));
            out[(size_t)b * Cout + o] = acc;
        }
    }
}

// ---- contiguous-row matvec, float4 ----
template <int ACT>
__device__ void mv4stage(const float* __restrict__ in, const float* __restrict__ w,
                         const float* __restrict__ bias, float* __restrict__ out,
                         int Cin, int Cout, int wv, int lane) {
    int n4 = Cin >> 2;
    for (int t = wv; t < 2 * Cout; t += NWV) {
        int b = t / Cout, o = t % Cout;
        const float4* wp = (const float4*)(w + (size_t)o * Cin);
        const float4* ip = (const float4*)(in + (size_t)b * Cin);
        float acc = 0.f;
        for (int k = lane; k < n4; k += 64) {
            float4 wv4 = wp[k];
            float4 iv = ip[k];
            acc += wv4.x * iv.x + wv4.y * iv.y + wv4.z * iv.z + wv4.w * iv.w;
        }
#pragma unroll
        for (int off = 32; off; off >>= 1) acc += __shfl_xor(acc, off);
        if (lane == 0) {
            acc += bias[o];
            if (ACT == 1) acc = fmaxf(acc, 0.f);
            if (ACT == 2) acc = 1.f / (1.f + expf(-acc));
            out[(size_t)b * Cout + o] = acc;
        }
    }
}

// ---- collapsed locally-connected conv (input spatially constant) ----
__device__ void localstage(const float* __restrict__ wl, const float* __restrict__ bl,
                           const float* __restrict__ v, float* __restrict__ h1,
                           int wv, int lane) {
    int e1 = lane + 64, e2 = lane + 128, e3 = lane + 192;
    int off0 = (lane / 14) * 50 + lane % 14;
    int off1 = (e1 / 14) * 50 + e1 % 14;
    int off2 = (e2 / 14) * 50 + e2 % 14;
    int off3 = (e3 / 14) * 50 + e3 % 14;   // valid for lane < 4 only
    for (int wk = wv; wk < LBL * HO * HO; wk += NWV) {
        int j = wk % HO; int t1 = wk / HO;
        int i = t1 % HO; int o = t1 / HO;
        int s0 = 25 - i, t0 = 25 - j;
        size_t base_ij = ((size_t)(i * HO + j) * LBL + o) * LBL;
        const float* pij = wl + base_ij * 2500 + s0 * 50 + t0;
        float acc0 = 0.f, acc1 = 0.f;
        for (int c = 0; c < LBL; ++c) {
            const float* p = pij + (size_t)c * 2500;
            float part = p[off0] + p[off1] + p[off2];
            if (lane < 4) part += p[off3];
            acc0 += v[c] * part;
            acc1 += v[LBL + c] * part;
        }
#pragma unroll
        for (int off = 32; off; off >>= 1) {
            acc0 += __shfl_xor(acc0, off);
            acc1 += __shfl_xor(acc1, off);
        }
        if (lane == 0) {
            float bv = bl[(o * HO + i) * HO + j];
            h1[(size_t)(0 * LBL + o) * 225 + i * HO + j] = acc0 + bv;
            h1[(size_t)(1 * LBL + o) * 225 + i * HO + j] = acc1 + bv;
        }
    }
}

// ---- fused wa channel-mix + conv3d-collapsed 9x9 conv, per-(b,o) block ----
__device__ void ninestage(const float* __restrict__ h1, const float* __restrict__ wa,
                          const float* __restrict__ ba, const float* __restrict__ wm,
                          const float* __restrict__ bm, float* __restrict__ h3,
                          float* smem, int tid) {
    int blk = blockIdx.x;
    if (blk >= 2 * LM) return;
    float* s1 = smem;              // 4725
    float* s2 = smem + 4725;       // 4725
    float* sw = smem + 9450;       // 1701
    float* swa = smem + 11151;     // 441
    int b = blk / LM, o = blk % LM;
    for (int k = tid; k < 4725; k += NT) s1[k] = h1[(size_t)b * 4725 + k];
    for (int k = tid; k < 441; k += NT) swa[k] = wa[k];
    for (int k = tid; k < 1701; k += NT) sw[k] = wm[((size_t)o * 1701 + k) * LBL + 10];
    __syncthreads();
    for (int k = tid; k < 4725; k += NT) {
        int c = k / 225, pix = k % 225;
        float acc = ba[c];
        for (int c2 = 0; c2 < LBL; ++c2)
            acc += swa[c * LBL + c2] * s1[c2 * 225 + pix];
        s2[k] = acc;
    }
    __syncthreads();
    if (tid < 225) {
        int i = tid / HO, j = tid % HO;
        float acc = bm[o];
        for (int c = 0; c < LBL; ++c) {
            const float* wp = sw + c * 81;
            const float* hp = s2 + c * 225;
#pragma unroll
            for (int di = 0; di < 9; ++di) {
                int y = i + di - 4;
                if (y < 0 || y >= HO) continue;
#pragma unroll
                for (int dj = 0; dj < 9; ++dj) {
                    int x = j + dj - 4;
                    if (x < 0 || x >= HO) continue;
                    acc += hp[y * HO + x] * wp[di * 9 + dj];
                }
            }
        }
        h3[((size_t)b * LM + o) * 225 + tid] = acc;
    }
}

// ---- wb mix + block-min(5) + softmax(105) ----
__device__ void finalstage(const float* __restrict__ h3, const float* __restrict__ wbw,
                           const float* __restrict__ bbv, float* __restrict__ out,
                           float* smem, int tid) {
    int blk = blockIdx.x;
    if (blk >= 2 * HO * 3) return;
    float* sv = smem;          // 105
    float* sred = smem + 112;  // 2 scalars
    int k = blk % 3; int t = blk / 3; int i = t % HO; int b = t / HO;
    int o = tid;
    if (o < LM) {
        float mn = 3.4e38f;
        for (int mm = 0; mm < MIX; ++mm) {
            int j = mm * 3 + k;
            float acc = bbv[o];
            const float* hp = h3 + (size_t)b * LM * 225 + i * HO + j;
            const float* wp = wbw + o * LM;
            for (int c = 0; c < LM; ++c) acc += wp[c] * hp[(size_t)c * 225];
            mn = fminf(mn, acc);
        }
        sv[o] = mn;
    }
    __syncthreads();
    if (tid < 64) {
        float m = -3.4e38f;
        for (int c = tid; c < LM; c += 64) m = fmaxf(m, sv[c]);
#pragma unroll
        for (int off = 32; off; off >>= 1) m = fmaxf(m, __shfl_xor(m, off));
        if (tid == 0) sred[0] = m;
    }
    __syncthreads();
    if (o < LM) sv[o] = expf(sv[o] - sred[0]);
    __syncthreads();
    if (tid < 64) {
        float s = 0.f;
        for (int c = tid; c < LM; c += 64) s += sv[c];
#pragma unroll
        for (int off = 32; off; off >>= 1) s += __shfl_xor(s, off);
        if (tid == 0) sred[1] = s;
    }
    __syncthreads();
    if (o < LM) out[(((size_t)b * LM + o) * HO + i) * 3 + k] = sv[o] / sred[1];
}

__global__ __launch_bounds__(NT, 1) void mega(Params p) {
    const int tid = threadIdx.x;
    const int gtid = blockIdx.x * NT + tid;
    const int wv = gtid >> 6;
    const int lane = tid & 63;
    __shared__ float smem[11592];

    convstage<1>(p.x, p.w[1], p.b[1], p.A, 3, 64, 14, 14, gtid);   gbar(p.bar, 0);
    convstage<1>(p.A, p.w[2], p.b[2], p.B, 64, 64, 14, 14, gtid);  gbar(p.bar, 1);
    convstage<2>(p.B, p.w[3], p.b[3], p.A, 64, 128, 14, 7, gtid);  gbar(p.bar, 2);
    convstage<1>(p.A, p.w[4], p.b[4], p.B, 128, 128, 7, 7, gtid);  gbar(p.bar, 3);
    convstage<2>(p.B, p.w[5], p.b[5], p.A, 128, 256, 7, 3, gtid);  gbar(p.bar, 4);
    convstage<1>(p.A, p.w[6], p.b[6], p.B, 256, 256, 3, 3, gtid);  gbar(p.bar, 5);
    convstage<1>(p.B, p.w[7], p.b[7], p.A, 256, 256, 3, 3, gtid);  gbar(p.bar, 6);

    mvstage<1, 2>(p.A, p.w[8],  p.b[8],  p.B, 256, 512, 9, 4, wv, lane); gbar(p.bar, 7);
    mvstage<1, 1>(p.B, p.w[9],  p.b[9],  p.A, 512, 512, 9, 4, wv, lane); gbar(p.bar, 8);
    mvstage<1, 1>(p.A, p.w[10], p.b[10], p.B, 512, 512, 9, 4, wv, lane); gbar(p.bar, 9);
    mvstage<1, 1>(p.B, p.w[11], p.b[11], p.A, 512, 512, 9, 4, wv, lane); gbar(p.bar, 10);
    mvstage<1, 1>(p.A, p.w[12], p.b[12], p.B, 512, 512, 9, 4, wv, lane); gbar(p.bar, 11);
    mvstage<1, 1>(p.B, p.w[13], p.b[13], p.A, 512, 512, 9, 4, wv, lane); gbar(p.bar, 12);
    mvstage<1, 1>(p.A, p.wf1, p.bf1, p.B, 512, 4096, 49, 24, wv, lane);  gbar(p.bar, 13);
    mv4stage<1>(p.B, p.wf2, p.bf2, p.A, 4096, 4096, wv, lane);           gbar(p.bar, 14);
    mv4stage<2>(p.A, p.wf3, p.bf3, p.v, 4096, LBL, wv, lane);            gbar(p.bar, 15);

    localstage(p.wl, p.bl, p.v, p.h1, wv, lane);                         gbar(p.bar, 16);
    ninestage(p.h1, p.wa, p.ba, p.wm, p.bm, p.h3, smem, tid);            gbar(p.bar, 17);
    finalstage(p.h3, p.wb, p.bb, p.out, smem, tid);
}

extern "C" void kernel_launch(void* const* d_in, const int* in_sizes, int n_in,
                              void* d_out, int out_size, void* d_ws, size_t ws_size,
                              hipStream_t stream) {
    Params p;
    p.x = (const float*)d_in[0];
    for (int i = 1; i <= 13; ++i) {
        p.w[i] = (const float*)d_in[2 * i - 1];
        p.b[i] = (const float*)d_in[2 * i];
    }
    p.wf1 = (const float*)d_in[27]; p.bf1 = (const float*)d_in[28];
    p.wf2 = (const float*)d_in[29]; p.bf2 = (const float*)d_in[30];
    p.wf3 = (const float*)d_in[31]; p.bf3 = (const float*)d_in[32];
    p.wl  = (const float*)d_in[33]; p.bl  = (const float*)d_in[34];
    p.wa  = (const float*)d_in[35]; p.ba  = (const float*)d_in[36];
    p.wm  = (const float*)d_in[37]; p.bm  = (const float*)d_in[38];
    p.wb  = (const float*)d_in[39]; p.bb  = (const float*)d_in[40];

    float* wsf = (float*)d_ws;
    p.bar = (int*)d_ws;            // 256 ints, zeroed below (captured in graph)
    p.A  = wsf + 256;              // 32768
    p.B  = wsf + 256 + 32768;      // 32768
    p.v  = wsf + 256 + 65536;      // 64
    p.h1 = wsf + 256 + 65600;      // 9472
    p.h3 = wsf + 256 + 75072;      // 47250
    p.out = (float*)d_out;

    hipMemsetAsync(d_ws, 0, 1024, stream);
    hipLaunchKernelGGL(mega, dim3(NB), dim3(NT), 0, stream, p);
}

// Round 4
// 1177.809 us; speedup vs baseline: 2.3801x; 2.3801x over previous
//
#include <hip/hip_runtime.h>
#include <math.h>

#define HO 15
#define LBL 21
#define MIX 5
#define LM 105   // LBL*MIX

__device__ __forceinline__ float max4(float a, float b, float c, float d) {
    return fmaxf(fmaxf(a, b), fmaxf(c, d));
}

// ---------------- 3x3 conv (pad 1) + relu; POOL=2 reads 2x2-maxpooled input view ----
template <int Cin, int Cout, int Hi, int H, int POOL>
__launch_bounds__(256)
__global__ void conv3(const float* __restrict__ in, const float* __restrict__ w,
                      const float* __restrict__ bias, float* __restrict__ out) {
    int idx = blockIdx.x * 256 + threadIdx.x;
    if (idx >= 2 * Cout * H * H) return;
    int x = idx % H; int t = idx / H;
    int y = t % H; t /= H;
    int o = t % Cout; int b = t / Cout;
    const float* ip = in + (size_t)b * Cin * Hi * Hi;
    const float* wp = w + (size_t)o * Cin * 9;
    float acc = bias[o];
#pragma unroll 4
    for (int c = 0; c < Cin; ++c) {
        const float* ic = ip + (size_t)c * Hi * Hi;
        const float* wc = wp + c * 9;
#pragma unroll
        for (int ky = 0; ky < 3; ++ky) {
            int yy = y + ky - 1;
            if (yy < 0 || yy >= H) continue;
#pragma unroll
            for (int kx = 0; kx < 3; ++kx) {
                int xx = x + kx - 1;
                if (xx < 0 || xx >= H) continue;
                float val;
                if (POOL == 1) {
                    val = ic[yy * Hi + xx];
                } else {
                    const float* q = ic + (2 * yy) * Hi + 2 * xx;
                    val = max4(q[0], q[1], q[Hi], q[Hi + 1]);
                }
                acc += val * wc[ky * 3 + kx];
            }
        }
    }
    out[idx] = fmaxf(acc, 0.f);
}

// ---------------- strided-tap matvec, both batches per wave, fully unrolled ----------
// out[b,o] = act( sum_c w[(o*Cin+c)*S + F] * in[b,c] + bias[o] )
template <int Cin, int ACT, int POOL>
__launch_bounds__(256)
__global__ void mv_tap(const float* __restrict__ in, const float* __restrict__ w,
                       const float* __restrict__ bias, float* __restrict__ out,
                       int Cout, int S, int F) {
    int wid = (blockIdx.x * 256 + threadIdx.x) >> 6;
    int lane = threadIdx.x & 63;
    if (wid >= Cout) return;
    int o = wid;
    constexpr int K = Cin / 64;
    float wv[K], i0[K], i1[K];
    const float* wp = w + ((size_t)o * Cin + lane) * S + F;
#pragma unroll
    for (int k = 0; k < K; ++k) wv[k] = wp[(size_t)64 * S * k];
#pragma unroll
    for (int k = 0; k < K; ++k) {
        int c = lane + 64 * k;
        if (POOL == 2) {
            const float* q0 = in + (size_t)(0 * Cin + c) * 9;
            const float* q1 = in + (size_t)(1 * Cin + c) * 9;
            i0[k] = max4(q0[0], q0[1], q0[3], q0[4]);
            i1[k] = max4(q1[0], q1[1], q1[3], q1[4]);
        } else {
            i0[k] = in[c];
            i1[k] = in[Cin + c];
        }
    }
    float a0 = 0.f, a1 = 0.f;
#pragma unroll
    for (int k = 0; k < K; ++k) { a0 += wv[k] * i0[k]; a1 += wv[k] * i1[k]; }
#pragma unroll
    for (int off = 32; off; off >>= 1) {
        a0 += __shfl_xor(a0, off);
        a1 += __shfl_xor(a1, off);
    }
    if (lane == 0) {
        float bv = bias[o];
        a0 += bv; a1 += bv;
        if (ACT == 1) { a0 = fmaxf(a0, 0.f); a1 = fmaxf(a1, 0.f); }
        if (ACT == 2) { a0 = 1.f / (1.f + expf(-a0)); a1 = 1.f / (1.f + expf(-a1)); }
        out[o] = a0;
        out[Cout + o] = a1;
    }
}

// ---------------- contiguous-row matvec, float4, both batches per wave --------------
template <int Cin, int ACT>
__launch_bounds__(256)
__global__ void mv_row(const float* __restrict__ in, const float* __restrict__ w,
                       const float* __restrict__ bias, float* __restrict__ out,
                       int Cout) {
    int wid = (blockIdx.x * 256 + threadIdx.x) >> 6;
    int lane = threadIdx.x & 63;
    if (wid >= Cout) return;
    int o = wid;
    const float4* wp = (const float4*)(w + (size_t)o * Cin) + lane;
    const float4* p0 = (const float4*)(in) + lane;
    const float4* p1 = (const float4*)(in + Cin) + lane;
    constexpr int K = Cin / 256;
    float a0 = 0.f, a1 = 0.f;
#pragma unroll 4
    for (int k = 0; k < K; ++k) {
        float4 wv = wp[64 * k];
        float4 x0 = p0[64 * k];
        float4 x1 = p1[64 * k];
        a0 += wv.x * x0.x + wv.y * x0.y + wv.z * x0.z + wv.w * x0.w;
        a1 += wv.x * x1.x + wv.y * x1.y + wv.z * x1.z + wv.w * x1.w;
    }
#pragma unroll
    for (int off = 32; off; off >>= 1) {
        a0 += __shfl_xor(a0, off);
        a1 += __shfl_xor(a1, off);
    }
    if (lane == 0) {
        float bv = bias[o];
        a0 += bv; a1 += bv;
        if (ACT == 1) { a0 = fmaxf(a0, 0.f); a1 = fmaxf(a1, 0.f); }
        if (ACT == 2) { a0 = 1.f / (1.f + expf(-a0)); a1 = 1.f / (1.f + expf(-a1)); }
        out[o] = a0;
        out[Cout + o] = a1;
    }
}

// ---------------- collapsed locally-connected conv (input spatially constant) -------
// h1[b,o,i,j] = sum_c v[b,c] * (14x14 window sum of wl[i,j,o,c]) + bl[o,i,j]
__launch_bounds__(256)
__global__ void localconv(const float* __restrict__ wl, const float* __restrict__ bl,
                          const float* __restrict__ v, float* __restrict__ h1) {
    int wid = (blockIdx.x * 256 + threadIdx.x) >> 6;
    int lane = threadIdx.x & 63;
    if (wid >= LBL * HO * HO) return;
    int j = wid % HO; int t1 = wid / HO;
    int i = t1 % HO; int o = t1 / HO;
    int s0 = 25 - i, t0 = 25 - j;
    int e1 = lane + 64, e2 = lane + 128, e3 = lane + 192;
    int off0 = (lane / 14) * 50 + lane % 14;
    int off1 = (e1 / 14) * 50 + e1 % 14;
    int off2 = (e2 / 14) * 50 + e2 % 14;
    int off3 = (lane < 4) ? ((e3 / 14) * 50 + e3 % 14) : off0;
    float m3 = (lane < 4) ? 1.f : 0.f;
    size_t base_ij = ((size_t)(i * HO + j) * LBL + o) * LBL;
    const float* pij = wl + base_ij * 2500 + s0 * 50 + t0;
    float a0 = 0.f, a1 = 0.f;
#pragma unroll 7
    for (int c = 0; c < LBL; ++c) {
        const float* p = pij + (size_t)c * 2500;
        float part = p[off0] + p[off1] + p[off2] + m3 * p[off3];
        a0 += v[c] * part;
        a1 += v[LBL + c] * part;
    }
#pragma unroll
    for (int off = 32; off; off >>= 1) {
        a0 += __shfl_xor(a0, off);
        a1 += __shfl_xor(a1, off);
    }
    if (lane == 0) {
        float bv = bl[(o * HO + i) * HO + j];
        h1[(size_t)(0 * LBL + o) * 225 + i * HO + j] = a0 + bv;
        h1[(size_t)(1 * LBL + o) * 225 + i * HO + j] = a1 + bv;
    }
}

// ---------------- fused wa channel-mix + conv3d-collapsed 9x9 conv ------------------
__launch_bounds__(256)
__global__ void conv9x9_fused(const float* __restrict__ h1, const float* __restrict__ wa,
                              const float* __restrict__ ba, const float* __restrict__ wm,
                              const float* __restrict__ bm, float* __restrict__ h3) {
    __shared__ float s1[LBL * 225];
    __shared__ float s2[LBL * 225];
    __shared__ float sw[LBL * 81];
    __shared__ float swa[LBL * LBL];
    int b = blockIdx.x / LM, o = blockIdx.x % LM;
    int tid = threadIdx.x;
    for (int k = tid; k < LBL * 225; k += 256) s1[k] = h1[(size_t)b * (LBL * 225) + k];
    for (int k = tid; k < LBL * LBL; k += 256) swa[k] = wa[k];
#pragma unroll 7
    for (int k = tid; k < LBL * 81; k += 256) sw[k] = wm[((size_t)o * (LBL * 81) + k) * LBL + 10];
    __syncthreads();
    for (int k = tid; k < LBL * 225; k += 256) {
        int c = k / 225, pix = k % 225;
        float acc = ba[c];
#pragma unroll 7
        for (int c2 = 0; c2 < LBL; ++c2)
            acc += swa[c * LBL + c2] * s1[c2 * 225 + pix];
        s2[k] = acc;
    }
    __syncthreads();
    if (tid >= 225) return;
    int i = tid / HO, j = tid % HO;
    float acc = bm[o];
    for (int c = 0; c < LBL; ++c) {
        const float* wp = sw + c * 81;
        const float* hp = s2 + c * 225;
#pragma unroll
        for (int di = 0; di < 9; ++di) {
            int y = i + di - 4;
            if (y < 0 || y >= HO) continue;
#pragma unroll
            for (int dj = 0; dj < 9; ++dj) {
                int x = j + dj - 4;
                if (x < 0 || x >= HO) continue;
                acc += hp[y * HO + x] * wp[di * 9 + dj];
            }
        }
    }
    h3[((size_t)b * LM + o) * 225 + tid] = acc;
}

// ---------------- wb mix + block-min(5) + softmax(105) ------------------------------
__launch_bounds__(128)
__global__ void final_k(const float* __restrict__ h3, const float* __restrict__ wbw,
                        const float* __restrict__ bbv, float* __restrict__ out) {
    __shared__ float sv[LM];
    __shared__ float sred[2];
    int blk = blockIdx.x;
    int k = blk % 3; int t = blk / 3; int i = t % HO; int b = t / HO;
    int o = threadIdx.x;
    if (o < LM) {
        float mn = 3.4e38f;
        for (int mm = 0; mm < MIX; ++mm) {
            int j = mm * 3 + k;
            float acc = bbv[o];
            const float* hp = h3 + (size_t)b * LM * 225 + i * HO + j;
            const float* wp = wbw + o * LM;
#pragma unroll 5
            for (int c = 0; c < LM; ++c) acc += wp[c] * hp[(size_t)c * 225];
            mn = fminf(mn, acc);
        }
        sv[o] = mn;
    }
    __syncthreads();
    if (o < 64) {
        float m = -3.4e38f;
        for (int c = o; c < LM; c += 64) m = fmaxf(m, sv[c]);
#pragma unroll
        for (int off = 32; off; off >>= 1) m = fmaxf(m, __shfl_xor(m, off));
        if (o == 0) sred[0] = m;
    }
    __syncthreads();
    if (o < LM) sv[o] = expf(sv[o] - sred[0]);
    __syncthreads();
    if (o < 64) {
        float s = 0.f;
        for (int c = o; c < LM; c += 64) s += sv[c];
#pragma unroll
        for (int off = 32; off; off >>= 1) s += __shfl_xor(s, off);
        if (o == 0) sred[1] = s;
    }
    __syncthreads();
    if (o < LM) out[(((size_t)b * LM + o) * HO + i) * 3 + k] = sv[o] / sred[1];
}

extern "C" void kernel_launch(void* const* d_in, const int* in_sizes, int n_in,
                              void* d_out, int out_size, void* d_ws, size_t ws_size,
                              hipStream_t stream) {
    const float* x = (const float*)d_in[0];
    const float* w[14]; const float* bs[14];
    for (int i = 1; i <= 13; ++i) {
        w[i]  = (const float*)d_in[2 * i - 1];
        bs[i] = (const float*)d_in[2 * i];
    }
    const float* wf1 = (const float*)d_in[27]; const float* bf1 = (const float*)d_in[28];
    const float* wf2 = (const float*)d_in[29]; const float* bf2 = (const float*)d_in[30];
    const float* wf3 = (const float*)d_in[31]; const float* bf3 = (const float*)d_in[32];
    const float* wl  = (const float*)d_in[33]; const float* bl  = (const float*)d_in[34];
    const float* wa  = (const float*)d_in[35]; const float* ba  = (const float*)d_in[36];
    const float* wm  = (const float*)d_in[37]; const float* bm  = (const float*)d_in[38];
    const float* wb  = (const float*)d_in[39]; const float* bb  = (const float*)d_in[40];

    float* wsf = (float*)d_ws;
    float* A  = wsf;                   // 32768
    float* B  = wsf + 32768;           // 32768
    float* v  = wsf + 65536;           // 64
    float* h1 = wsf + 65600;           // 9472
    float* h3 = wsf + 75072;           // 47250

    auto cdiv = [](int a, int b) { return (a + b - 1) / b; };

    // VGG trunk; maxpools folded into consumer reads (POOL=2)
    conv3<3,   64, 14, 14, 1><<<cdiv(2 * 64 * 196, 256), 256, 0, stream>>>(x, w[1], bs[1], A);
    conv3<64,  64, 14, 14, 1><<<cdiv(2 * 64 * 196, 256), 256, 0, stream>>>(A, w[2], bs[2], B);
    conv3<64, 128, 14,  7, 2><<<cdiv(2 * 128 * 49, 256), 256, 0, stream>>>(B, w[3], bs[3], A);
    conv3<128,128,  7,  7, 1><<<cdiv(2 * 128 * 49, 256), 256, 0, stream>>>(A, w[4], bs[4], B);
    conv3<128,256,  7,  3, 2><<<cdiv(2 * 256 * 9, 256), 256, 0, stream>>>(B, w[5], bs[5], A);
    conv3<256,256,  3,  3, 1><<<cdiv(2 * 256 * 9, 256), 256, 0, stream>>>(A, w[6], bs[6], B);
    conv3<256,256,  3,  3, 1><<<cdiv(2 * 256 * 9, 256), 256, 0, stream>>>(B, w[7], bs[7], A);

    // 1x1-spatial chain: center-tap matvecs, both batches per wave
    mv_tap<256, 1, 2><<<cdiv(512 * 64, 256), 256, 0, stream>>>(A, w[8],  bs[8],  B, 512, 9, 4);
    mv_tap<512, 1, 1><<<cdiv(512 * 64, 256), 256, 0, stream>>>(B, w[9],  bs[9],  A, 512, 9, 4);
    mv_tap<512, 1, 1><<<cdiv(512 * 64, 256), 256, 0, stream>>>(A, w[10], bs[10], B, 512, 9, 4);
    mv_tap<512, 1, 1><<<cdiv(512 * 64, 256), 256, 0, stream>>>(B, w[11], bs[11], A, 512, 9, 4);
    mv_tap<512, 1, 1><<<cdiv(512 * 64, 256), 256, 0, stream>>>(A, w[12], bs[12], B, 512, 9, 4);
    mv_tap<512, 1, 1><<<cdiv(512 * 64, 256), 256, 0, stream>>>(B, w[13], bs[13], A, 512, 9, 4);
    mv_tap<512, 1, 1><<<cdiv(4096 * 64, 256), 256, 0, stream>>>(A, wf1, bf1, B, 4096, 49, 24);
    mv_row<4096, 1><<<cdiv(4096 * 64, 256), 256, 0, stream>>>(B, wf2, bf2, A, 4096);
    mv_row<4096, 2><<<cdiv(21 * 64, 256), 256, 0, stream>>>(A, wf3, bf3, v, 21);

    // collapsed locally-connected conv
    localconv<<<cdiv(LBL * 225 * 64, 256), 256, 0, stream>>>(wl, bl, v, h1);
    // fused wa mix + 9x9 conv (conv3d slice kw=10)
    conv9x9_fused<<<2 * LM, 256, 0, stream>>>(h1, wa, ba, wm, bm, h3);
    // wb mix + block-min + softmax
    final_k<<<90, 128, 0, stream>>>(h3, wb, bb, (float*)d_out);
}